// Round 1
// baseline (1246.790 us; speedup 1.0000x reference)
//
#include <hip/hip_runtime.h>

#define NN 120000
#define DD 64
#define EE 1000000
#define NL 3
#define OUTD 256   // (NL+1)*DD

// ---------------- setup kernels ----------------

__global__ void k_deg(const int* __restrict__ col, float* __restrict__ deg) {
    int i = blockIdx.x * blockDim.x + threadIdx.x;
    int stride = gridDim.x * blockDim.x;
    for (int e = i; e < EE; e += stride)
        atomicAdd(&deg[col[e]], 1.0f);
}

__global__ void k_dinv(float* __restrict__ deg) {
    int n = blockIdx.x * blockDim.x + threadIdx.x;
    if (n < NN) {
        float d = deg[n];
        deg[n] = (d > 0.0f) ? rsqrtf(d) : 0.0f;   // deg>=1 when >0, so max(deg,1)=deg
    }
}

__global__ void k_norm(const int* __restrict__ row, const int* __restrict__ col,
                       const float* __restrict__ dinv,
                       float* __restrict__ norm, float* __restrict__ c) {
    int i = blockIdx.x * blockDim.x + threadIdx.x;
    int stride = gridDim.x * blockDim.x;
    for (int e = i; e < EE; e += stride) {
        float nr = dinv[row[e]] * dinv[col[e]];
        norm[e] = nr;
        atomicAdd(&c[row[e]], nr);
    }
}

__global__ void k_copy_emb(const float* __restrict__ emb, float* __restrict__ out) {
    int i = blockIdx.x * blockDim.x + threadIdx.x;
    int stride = gridDim.x * blockDim.x;
    const float4* e4 = (const float4*)emb;
    float4* o4 = (float4*)out;
    const int total = NN * (DD / 4);
    for (int t = i; t < total; t += stride) {
        int n = t / (DD / 4);
        int d4 = t % (DD / 4);
        o4[n * (OUTD / 4) + d4] = e4[t];
    }
}

// ---------------- edge scatter: S1[row] += norm * x[col] ----------------
// one wave (64 lanes) per edge; lane = feature dim. x read from out's column
// block for the current layer.

__global__ void k_scatter(const int* __restrict__ row, const int* __restrict__ col,
                          const float* __restrict__ norm,
                          const float* __restrict__ out, int xoff,
                          float* __restrict__ S1) {
    int tid = blockIdx.x * blockDim.x + threadIdx.x;
    int lane = tid & 63;
    int wave = tid >> 6;
    int nwaves = (gridDim.x * blockDim.x) >> 6;
    // contiguous chunk per wave for edge-array L1 locality
    int chunk = (EE + nwaves - 1) / nwaves;
    int e0 = wave * chunk;
    int e1 = min(EE, e0 + chunk);
    for (int e = e0; e < e1; ++e) {
        int r = row[e];
        int cc = col[e];
        float nr = norm[e];
        float v = out[cc * OUTD + xoff + lane];
        atomicAdd(&S1[r * DD + lane], nr * v);
    }
}

// ---------------- dense per-node: agg = S1@W1^T + (x*S1)@W2^T + c*(b1+b2) ----------------
// one wave per node, lane = output feature j. W1/W2 staged in LDS with +1 pad.

__global__ void __launch_bounds__(256) k_dense(
    const float* __restrict__ S1, const float* __restrict__ c,
    const float* __restrict__ W1, const float* __restrict__ b1,
    const float* __restrict__ W2, const float* __restrict__ b2,
    float* out, int layer) {
    __shared__ float w1s[DD][DD + 1];
    __shared__ float w2s[DD][DD + 1];
    __shared__ float s1s[4][DD];
    __shared__ float ps[4][DD];

    const float* W1l = W1 + layer * DD * DD;
    const float* W2l = W2 + layer * DD * DD;
    for (int t = threadIdx.x; t < DD * DD; t += blockDim.x) {
        int j = t / DD, k = t % DD;
        w1s[j][k] = W1l[t];
        w2s[j][k] = W2l[t];
    }
    __syncthreads();

    int wib = threadIdx.x >> 6;   // wave in block (0..3)
    int lane = threadIdx.x & 63;
    int nwaves = (gridDim.x * blockDim.x) >> 6;
    float bb = b1[layer * DD + lane] + b2[layer * DD + lane];
    int xoff = layer * DD;
    int ooff = (layer + 1) * DD;

    for (int n = blockIdx.x * 4 + wib; n < NN; n += nwaves) {
        float s1 = S1[n * DD + lane];
        float xv = out[n * OUTD + xoff + lane];
        s1s[wib][lane] = s1;
        ps[wib][lane] = xv * s1;
        float acc = c[n] * bb;
        #pragma unroll
        for (int k = 0; k < DD; ++k) {
            acc += s1s[wib][k] * w1s[lane][k] + ps[wib][k] * w2s[lane][k];
        }
        float r = (acc >= 0.0f) ? acc : 0.2f * acc;
        out[n * OUTD + ooff + lane] = r;
    }
}

// ---------------- launch ----------------

extern "C" void kernel_launch(void* const* d_in, const int* in_sizes, int n_in,
                              void* d_out, int out_size, void* d_ws, size_t ws_size,
                              hipStream_t stream) {
    const int*   ei  = (const int*)d_in[0];     // [2, E]: row = ei, col = ei + E
    const float* emb = (const float*)d_in[1];   // [N, D]
    const float* W1  = (const float*)d_in[2];   // [3, D, D]
    const float* b1  = (const float*)d_in[3];   // [3, D]
    const float* W2  = (const float*)d_in[4];   // [3, D, D]
    const float* b2  = (const float*)d_in[5];   // [3, D]
    float* out = (float*)d_out;                 // [N, 256]

    const int* row = ei;
    const int* col = ei + EE;

    // workspace layout (floats): deg/dinv | c | norm | S1
    float* deg  = (float*)d_ws;          // NN
    float* cbuf = deg + NN;              // NN
    float* norm = cbuf + NN;             // EE
    float* S1   = norm + EE;             // NN*DD
    size_t total_f = (size_t)NN * 2 + EE + (size_t)NN * DD;

    hipMemsetAsync(d_ws, 0, total_f * sizeof(float), stream);

    k_deg<<<2048, 256, 0, stream>>>(col, deg);
    k_dinv<<<(NN + 255) / 256, 256, 0, stream>>>(deg);
    k_norm<<<2048, 256, 0, stream>>>(row, col, deg, norm, cbuf);
    k_copy_emb<<<2048, 256, 0, stream>>>(emb, out);

    for (int layer = 0; layer < NL; ++layer) {
        if (layer > 0)
            hipMemsetAsync(S1, 0, (size_t)NN * DD * sizeof(float), stream);
        k_scatter<<<4096, 256, 0, stream>>>(row, col, norm, out, layer * DD, S1);
        k_dense<<<2048, 256, 0, stream>>>(S1, cbuf, W1, b1, W2, b2, out, layer);
    }
}

// Round 2
// 884.385 us; speedup vs baseline: 1.4098x; 1.4098x over previous
//
#include <hip/hip_runtime.h>

#define NN 120000
#define DD 64
#define EE 1000000
#define NL 3
#define OUTD 256     // (NL+1)*DD
#define PAD 68       // LDS row pad: 16B-aligned float4 reads, only 2-way bank aliasing (free)
#define NB 469       // ceil(NN/256)

// ---------------- CSR build ----------------

__global__ void k_degcnt(const int* __restrict__ row, const int* __restrict__ col,
                         int* __restrict__ deg_i, int* __restrict__ cnt) {
    int i = blockIdx.x * blockDim.x + threadIdx.x;
    int stride = gridDim.x * blockDim.x;
    for (int e = i; e < EE; e += stride) {
        atomicAdd(&deg_i[col[e]], 1);
        atomicAdd(&cnt[row[e]], 1);
    }
}

__global__ void k_dinv(const int* __restrict__ deg_i, float* __restrict__ dinv) {
    int n = blockIdx.x * blockDim.x + threadIdx.x;
    if (n < NN) {
        int d = deg_i[n];
        dinv[n] = (d > 0) ? rsqrtf((float)d) : 0.0f;
    }
}

// block-local inclusive scan -> exclusive prefix within block + block sums
__global__ void k_scanA(const int* __restrict__ cnt, int* __restrict__ row_ptr,
                        int* __restrict__ bsum) {
    __shared__ int sc[256];
    int t = threadIdx.x;
    int i = blockIdx.x * 256 + t;
    int v = (i < NN) ? cnt[i] : 0;
    sc[t] = v;
    __syncthreads();
    for (int off = 1; off < 256; off <<= 1) {
        int u = (t >= off) ? sc[t - off] : 0;
        __syncthreads();
        sc[t] += u;
        __syncthreads();
    }
    if (i < NN) row_ptr[i] = sc[t] - v;          // exclusive, block-local
    if (t == 255) bsum[blockIdx.x] = sc[255];
}

__global__ void k_scanB(int* __restrict__ bsum, int* __restrict__ row_ptr) {
    __shared__ int sc[512];
    int t = threadIdx.x;
    int v = (t < NB) ? bsum[t] : 0;
    sc[t] = v;
    __syncthreads();
    for (int off = 1; off < 512; off <<= 1) {
        int u = (t >= off) ? sc[t - off] : 0;
        __syncthreads();
        sc[t] += u;
        __syncthreads();
    }
    if (t < NB) bsum[t] = sc[t] - v;             // exclusive block offsets, in place
    if (t == 0) row_ptr[NN] = EE;
}

__global__ void k_scanC(int* __restrict__ row_ptr, const int* __restrict__ bsum) {
    int i = blockIdx.x * blockDim.x + threadIdx.x;
    if (i < NN) row_ptr[i] += bsum[i >> 8];
}

// scatter edges into CSR slots; store {col_bits, norm} packed as float2
__global__ void k_fill(const int* __restrict__ row, const int* __restrict__ col,
                       const float* __restrict__ dinv, const int* __restrict__ row_ptr,
                       int* __restrict__ fill, float2* __restrict__ csr) {
    int i = blockIdx.x * blockDim.x + threadIdx.x;
    int stride = gridDim.x * blockDim.x;
    for (int e = i; e < EE; e += stride) {
        int r = row[e], c = col[e];
        int pos = row_ptr[r] + atomicAdd(&fill[r], 1);
        csr[pos] = make_float2(__int_as_float(c), dinv[r] * dinv[c]);
    }
}

__global__ void k_copy_emb(const float* __restrict__ emb, float* __restrict__ out) {
    int i = blockIdx.x * blockDim.x + threadIdx.x;
    int stride = gridDim.x * blockDim.x;
    const float4* e4 = (const float4*)emb;
    float4* o4 = (float4*)out;
    const int total = NN * (DD / 4);
    for (int t = i; t < total; t += stride) {
        int n = t / (DD / 4);
        int d4 = t % (DD / 4);
        o4[n * (OUTD / 4) + d4] = e4[t];
    }
}

// ---------------- fused per-layer: CSR gather + dense ----------------
// Block = 256 threads = 4 waves, owns 64 consecutive nodes.
// Phase 1: wave w gathers nodes w*16..w*16+15 (lane = feature), writes s1/p tiles to LDS.
// Phase 2: register-tiled [64x64]@[64x64]^T x2 GEMM; 4x4 microtile per thread.

__global__ void __launch_bounds__(256, 4) k_layer(
    const int* __restrict__ row_ptr, const float2* __restrict__ csr,
    const float* __restrict__ W1, const float* __restrict__ b1,
    const float* __restrict__ W2, const float* __restrict__ b2,
    float* __restrict__ out, int layer)
{
    __shared__ float s1t[64][PAD];
    __shared__ float pt[64][PAD];
    __shared__ float cs[64];

    const int lane = threadIdx.x & 63;
    const int wib  = threadIdx.x >> 6;
    const int n0   = blockIdx.x * 64;
    const float* __restrict__ x = out + layer * DD;        // x row n at x[n*OUTD + d]
    float* __restrict__ y = out + (layer + 1) * DD;
    const float* __restrict__ W1l = W1 + layer * DD * DD;
    const float* __restrict__ W2l = W2 + layer * DD * DD;

    // ---- phase 1: edge gather ----
    for (int i = 0; i < 16; ++i) {
        const int nl = wib * 16 + i;
        const int n  = n0 + nl;
        const int beg = row_ptr[n], end = row_ptr[n + 1];
        float acc = 0.f, cacc = 0.f;
        int e = beg;
        for (; e + 4 <= end; e += 4) {               // 4 gathers in flight per wave
            float2 q0 = csr[e], q1 = csr[e + 1], q2 = csr[e + 2], q3 = csr[e + 3];
            float v0 = x[__float_as_int(q0.x) * OUTD + lane];
            float v1 = x[__float_as_int(q1.x) * OUTD + lane];
            float v2 = x[__float_as_int(q2.x) * OUTD + lane];
            float v3 = x[__float_as_int(q3.x) * OUTD + lane];
            acc += q0.y * v0 + q1.y * v1 + q2.y * v2 + q3.y * v3;
            cacc += q0.y + q1.y + q2.y + q3.y;
        }
        for (; e < end; ++e) {
            float2 q = csr[e];
            acc += q.y * x[__float_as_int(q.x) * OUTD + lane];
            cacc += q.y;
        }
        s1t[nl][lane] = acc;
        pt[nl][lane]  = acc * x[n * OUTD + lane];
        if (lane == 0) cs[nl] = cacc;
    }
    __syncthreads();

    // ---- phase 2: agg = S1@W1^T + P@W2^T + c*(b1+b2) ----
    const int tf = threadIdx.x & 15;    // feature group: features 4*tf+j
    const int tn = threadIdx.x >> 4;    // node group:    nodes    4*tn+i
    float acc[4][4];
    #pragma unroll
    for (int i = 0; i < 4; ++i)
        #pragma unroll
        for (int j = 0; j < 4; ++j) acc[i][j] = 0.f;

    for (int k4 = 0; k4 < 16; ++k4) {
        float4 a[4], p[4], wa[4], wb[4];
        #pragma unroll
        for (int i = 0; i < 4; ++i) {
            a[i] = *(const float4*)&s1t[4 * tn + i][4 * k4];
            p[i] = *(const float4*)&pt [4 * tn + i][4 * k4];
        }
        #pragma unroll
        for (int j = 0; j < 4; ++j) {
            wa[j] = *(const float4*)&W1l[(4 * tf + j) * DD + 4 * k4];
            wb[j] = *(const float4*)&W2l[(4 * tf + j) * DD + 4 * k4];
        }
        #pragma unroll
        for (int i = 0; i < 4; ++i)
            #pragma unroll
            for (int j = 0; j < 4; ++j) {
                acc[i][j] += a[i].x * wa[j].x + a[i].y * wa[j].y
                           + a[i].z * wa[j].z + a[i].w * wa[j].w
                           + p[i].x * wb[j].x + p[i].y * wb[j].y
                           + p[i].z * wb[j].z + p[i].w * wb[j].w;
            }
    }

    float bbj[4];
    #pragma unroll
    for (int j = 0; j < 4; ++j) {
        int f = 4 * tf + j;
        bbj[j] = b1[layer * DD + f] + b2[layer * DD + f];
    }
    #pragma unroll
    for (int i = 0; i < 4; ++i) {
        int nl = 4 * tn + i;
        float c = cs[nl];
        float4 r;
        float t0 = acc[i][0] + c * bbj[0]; r.x = t0 >= 0.f ? t0 : 0.2f * t0;
        float t1 = acc[i][1] + c * bbj[1]; r.y = t1 >= 0.f ? t1 : 0.2f * t1;
        float t2 = acc[i][2] + c * bbj[2]; r.z = t2 >= 0.f ? t2 : 0.2f * t2;
        float t3 = acc[i][3] + c * bbj[3]; r.w = t3 >= 0.f ? t3 : 0.2f * t3;
        *(float4*)&y[(n0 + nl) * OUTD + 4 * tf] = r;
    }
}

// ---------------- launch ----------------

extern "C" void kernel_launch(void* const* d_in, const int* in_sizes, int n_in,
                              void* d_out, int out_size, void* d_ws, size_t ws_size,
                              hipStream_t stream) {
    const int*   ei  = (const int*)d_in[0];     // [2, E]: row = ei, col = ei + E
    const float* emb = (const float*)d_in[1];   // [N, D]
    const float* W1  = (const float*)d_in[2];   // [3, D, D]
    const float* b1  = (const float*)d_in[3];   // [3, D]
    const float* W2  = (const float*)d_in[4];   // [3, D, D]
    const float* b2  = (const float*)d_in[5];   // [3, D]
    float* out = (float*)d_out;                 // [N, 256]

    const int* row = ei;
    const int* col = ei + EE;

    // workspace layout
    float2* csr   = (float2*)d_ws;              // EE float2 (8 MB)
    int* ibase    = (int*)(csr + EE);
    int* deg_i    = ibase;                      // NN
    int* cnt      = deg_i + NN;                 // NN
    int* fill     = cnt + NN;                   // NN
    int* row_ptr  = fill + NN;                  // NN+1
    int* bsum     = row_ptr + NN + 1;           // 512
    float* dinv   = (float*)(bsum + 512);       // NN

    // zero the three atomic-counter arrays (contiguous)
    hipMemsetAsync(ibase, 0, (size_t)3 * NN * sizeof(int), stream);

    k_degcnt<<<1024, 256, 0, stream>>>(row, col, deg_i, cnt);
    k_dinv<<<NB, 256, 0, stream>>>(deg_i, dinv);
    k_scanA<<<NB, 256, 0, stream>>>(cnt, row_ptr, bsum);
    k_scanB<<<1, 512, 0, stream>>>(bsum, row_ptr);
    k_scanC<<<NB, 256, 0, stream>>>(row_ptr, bsum);
    k_fill<<<1024, 256, 0, stream>>>(row, col, dinv, row_ptr, fill, csr);
    k_copy_emb<<<2048, 256, 0, stream>>>(emb, out);

    for (int layer = 0; layer < NL; ++layer) {
        k_layer<<<NN / 64, 256, 0, stream>>>(row_ptr, csr, W1, b1, W2, b2, out, layer);
    }
}